// Round 1
// baseline (2081.155 us; speedup 1.0000x reference)
//
#include <hip/hip_runtime.h>
#include <hip/hip_bf16.h>

typedef __bf16 bf16;
typedef __attribute__((ext_vector_type(8))) __bf16 bf16x8;
typedef __attribute__((ext_vector_type(4))) float f32x4;

constexpr int kH = 1024;   // hidden = input = output dim
constexpr int kB = 512;    // batch
constexpr int kT = 8;      // timesteps actually used (= nlayers in reference loop)
constexpr int kL = 8;      // layers
constexpr int kS = 128;    // seq len of x

constexpr int BM = 64, BN = 128, BK = 32;
constexpr int LDA = BK + 8;   // padded LDS k-stride (bf16 elems) -> 2-way-max bank aliasing
constexpr int LDB = BK + 8;

__device__ __forceinline__ float sigmoidf_(float v) { return 1.0f / (1.0f + __expf(-v)); }

__device__ __forceinline__ bf16x8 cvt8(float4 a, float4 b) {
  bf16x8 o;
  o[0] = (bf16)a.x; o[1] = (bf16)a.y; o[2] = (bf16)a.z; o[3] = (bf16)a.w;
  o[4] = (bf16)b.x; o[5] = (bf16)b.y; o[6] = (bf16)b.z; o[7] = (bf16)b.w;
  return o;
}

// Transpose+convert each 1024x1024 f32 W (row-major KxN) -> bf16 W^T (NxK).
// mats 0..47 = {Wxz,Whz,Wxr,Whr,Wxh,Whh}[mat/8] layer (mat%8); mat 48 = Why.
__global__ __launch_bounds__(256) void wconv_kernel(
    const float* __restrict__ Wxz, const float* __restrict__ Whz,
    const float* __restrict__ Wxr, const float* __restrict__ Whr,
    const float* __restrict__ Wxh, const float* __restrict__ Whh,
    const float* __restrict__ Why, bf16* __restrict__ wt) {
  __shared__ float tile[64][65];
  int mat = blockIdx.z;
  const float* src;
  if (mat < 48) {
    int g = mat >> 3;
    const float* bases[6] = {Wxz, Whz, Wxr, Whr, Wxh, Whh};
    src = bases[g] + (size_t)(mat & 7) * kH * kH;
  } else {
    src = Why;
  }
  bf16* dst = wt + (size_t)mat * kH * kH;
  int k0 = blockIdx.x * 64;   // source row (K) range
  int n0 = blockIdx.y * 64;   // source col (N) range
  int tid = threadIdx.x;
  int cl = (tid & 15) * 4;
  int rw = tid >> 4;
#pragma unroll
  for (int i = 0; i < 4; ++i) {
    int r = rw + i * 16;
    float4 v = *(const float4*)(src + (size_t)(k0 + r) * kH + n0 + cl);
    tile[r][cl] = v.x; tile[r][cl + 1] = v.y; tile[r][cl + 2] = v.z; tile[r][cl + 3] = v.w;
  }
  __syncthreads();
#pragma unroll
  for (int p = 0; p < 2; ++p) {
    int idx = p * 256 + tid;
    int n = idx >> 3;
    int koff = (idx & 7) * 8;
    bf16x8 o;
#pragma unroll
    for (int i = 0; i < 8; ++i) o[i] = (bf16)tile[koff + i][n];
    *(bf16x8*)(dst + (size_t)(n0 + n) * kH + k0 + koff) = o;
  }
}

// Phase 1 of GRU cell (t,l): z = sigmoid(inp@Wxz + hp@Whz + bz),
// r = sigmoid(inp@Wxr + hp@Whr + br), c1 = inp@Wxh.
// Stores Z (f32), C1 (f32), RH = r*hp (bf16) into per-cell ws slots.
__global__ __launch_bounds__(256, 2) void gru_phase1(
    const float* __restrict__ x, const float* __restrict__ hprev,
    const float* __restrict__ hseq, const bf16* __restrict__ wt,
    const float* __restrict__ b_z, const float* __restrict__ b_r,
    float* __restrict__ Zs, float* __restrict__ C1s, bf16* __restrict__ RHs,
    int diag, int t_lo) {
  int cell = blockIdx.z;
  int t = t_lo + cell;
  int l = diag - t;
  const float* inp; int inp_stride;
  if (l == 0) { inp = x + (size_t)t * kH; inp_stride = kS * kH; }
  else        { inp = hseq + ((size_t)((l - 1) * kT + t)) * kB * kH; inp_stride = kH; }
  const float* hp = (t == 0) ? hprev + (size_t)l * kB * kH
                             : hseq + ((size_t)(l * kT + (t - 1))) * kB * kH;
  const bf16* Wp[5];
#pragma unroll
  for (int g = 0; g < 5; ++g) Wp[g] = wt + ((size_t)g * 8 + l) * kH * kH;
  float* Zc  = Zs  + (size_t)cell * kB * kH;
  float* C1c = C1s + (size_t)cell * kB * kH;
  bf16*  RHc = RHs + (size_t)cell * kB * kH;

  __shared__ bf16 sInp[BM * LDA];
  __shared__ bf16 sHp[BM * LDA];
  __shared__ bf16 sB[5][BN * LDB];

  int tid = threadIdx.x;
  int lane = tid & 63;
  int wv = tid >> 6;
  int bm0 = blockIdx.x * BM;
  int bn0 = blockIdx.y * BN;

  f32x4 zacc[4][2] = {};
  f32x4 racc[4][2] = {};
  f32x4 cacc[4][2] = {};

  int sr = tid >> 2;        // 0..63
  int sc = (tid & 3) * 8;   // 0,8,16,24

  for (int k0 = 0; k0 < kH; k0 += BK) {
    {
      const float* pi = inp + (size_t)(bm0 + sr) * inp_stride + k0 + sc;
      float4 a0 = *(const float4*)pi;
      float4 a1 = *(const float4*)(pi + 4);
      *(bf16x8*)&sInp[sr * LDA + sc] = cvt8(a0, a1);
      const float* ph = hp + (size_t)(bm0 + sr) * kH + k0 + sc;
      float4 h0 = *(const float4*)ph;
      float4 h1 = *(const float4*)(ph + 4);
      *(bf16x8*)&sHp[sr * LDA + sc] = cvt8(h0, h1);
    }
#pragma unroll
    for (int g = 0; g < 5; ++g) {
#pragma unroll
      for (int p = 0; p < 2; ++p) {
        int idx = p * 256 + tid;
        int r = idx >> 2;
        int c = (idx & 3) * 8;
        *(bf16x8*)&sB[g][r * LDB + c] =
            *(const bf16x8*)(Wp[g] + (size_t)(bn0 + r) * kH + k0 + c);
      }
    }
    __syncthreads();
    int frow = lane & 15;
    int fk = (lane >> 4) * 8;
    bf16x8 ai[4], ah[4];
#pragma unroll
    for (int m = 0; m < 4; ++m) {
      ai[m] = *(const bf16x8*)&sInp[(m * 16 + frow) * LDA + fk];
      ah[m] = *(const bf16x8*)&sHp[(m * 16 + frow) * LDA + fk];
    }
#pragma unroll
    for (int nf = 0; nf < 2; ++nf) {
      int nr = wv * 32 + nf * 16 + frow;
      bf16x8 bxz = *(const bf16x8*)&sB[0][nr * LDB + fk];
      bf16x8 bhz = *(const bf16x8*)&sB[1][nr * LDB + fk];
      bf16x8 bxr = *(const bf16x8*)&sB[2][nr * LDB + fk];
      bf16x8 bhr = *(const bf16x8*)&sB[3][nr * LDB + fk];
      bf16x8 bxh = *(const bf16x8*)&sB[4][nr * LDB + fk];
#pragma unroll
      for (int m = 0; m < 4; ++m) {
        zacc[m][nf] = __builtin_amdgcn_mfma_f32_16x16x32_bf16(ai[m], bxz, zacc[m][nf], 0, 0, 0);
        zacc[m][nf] = __builtin_amdgcn_mfma_f32_16x16x32_bf16(ah[m], bhz, zacc[m][nf], 0, 0, 0);
        racc[m][nf] = __builtin_amdgcn_mfma_f32_16x16x32_bf16(ai[m], bxr, racc[m][nf], 0, 0, 0);
        racc[m][nf] = __builtin_amdgcn_mfma_f32_16x16x32_bf16(ah[m], bhr, racc[m][nf], 0, 0, 0);
        cacc[m][nf] = __builtin_amdgcn_mfma_f32_16x16x32_bf16(ai[m], bxh, cacc[m][nf], 0, 0, 0);
      }
    }
    __syncthreads();
  }
  // epilogue: C/D layout col=lane&15, row=(lane>>4)*4+q (m89-verified)
  int frow = lane & 15;
  int rbase = (lane >> 4) * 4;
#pragma unroll
  for (int m = 0; m < 4; ++m) {
#pragma unroll
    for (int nf = 0; nf < 2; ++nf) {
      int gcol = bn0 + wv * 32 + nf * 16 + frow;
      float bz = b_z[l * kH + gcol];
      float br = b_r[l * kH + gcol];
#pragma unroll
      for (int q = 0; q < 4; ++q) {
        int grow = bm0 + m * 16 + rbase + q;
        size_t off = (size_t)grow * kH + gcol;
        float z = sigmoidf_(zacc[m][nf][q] + bz);
        float r = sigmoidf_(racc[m][nf][q] + br);
        float hpv = hp[off];
        Zc[off] = z;
        C1c[off] = cacc[m][nf][q];
        RHc[off] = (bf16)(r * hpv);
      }
    }
  }
}

// Phase 2: h = (1-z)*hp + z*tanh(C1 + RH@Whh + bh); writes h_seq[l][t] (+ h_current at t==7)
__global__ __launch_bounds__(256, 2) void gru_phase2(
    const float* __restrict__ hprev, float* __restrict__ hseq,
    float* __restrict__ hcur, const bf16* __restrict__ wt,
    const float* __restrict__ b_h, const float* __restrict__ Zs,
    const float* __restrict__ C1s, const bf16* __restrict__ RHs,
    int diag, int t_lo) {
  int cell = blockIdx.z;
  int t = t_lo + cell;
  int l = diag - t;
  const bf16* Whh = wt + ((size_t)5 * 8 + l) * kH * kH;
  const float* hp = (t == 0) ? hprev + (size_t)l * kB * kH
                             : hseq + ((size_t)(l * kT + (t - 1))) * kB * kH;
  float* hout = hseq + ((size_t)(l * kT + t)) * kB * kH;
  const float* Zc  = Zs  + (size_t)cell * kB * kH;
  const float* C1c = C1s + (size_t)cell * kB * kH;
  const bf16*  RHc = RHs + (size_t)cell * kB * kH;

  __shared__ bf16 sA[BM * LDA];
  __shared__ bf16 sB[BN * LDB];

  int tid = threadIdx.x;
  int lane = tid & 63;
  int wv = tid >> 6;
  int bm0 = blockIdx.x * BM;
  int bn0 = blockIdx.y * BN;

  f32x4 acc[4][2] = {};
  int sr = tid >> 2;
  int sc = (tid & 3) * 8;

  for (int k0 = 0; k0 < kH; k0 += BK) {
    *(bf16x8*)&sA[sr * LDA + sc] = *(const bf16x8*)(RHc + (size_t)(bm0 + sr) * kH + k0 + sc);
#pragma unroll
    for (int p = 0; p < 2; ++p) {
      int idx = p * 256 + tid;
      int r = idx >> 2;
      int c = (idx & 3) * 8;
      *(bf16x8*)&sB[r * LDB + c] = *(const bf16x8*)(Whh + (size_t)(bn0 + r) * kH + k0 + c);
    }
    __syncthreads();
    int frow = lane & 15;
    int fk = (lane >> 4) * 8;
    bf16x8 a[4];
#pragma unroll
    for (int m = 0; m < 4; ++m) a[m] = *(const bf16x8*)&sA[(m * 16 + frow) * LDA + fk];
#pragma unroll
    for (int nf = 0; nf < 2; ++nf) {
      int nr = wv * 32 + nf * 16 + frow;
      bf16x8 b = *(const bf16x8*)&sB[nr * LDB + fk];
#pragma unroll
      for (int m = 0; m < 4; ++m)
        acc[m][nf] = __builtin_amdgcn_mfma_f32_16x16x32_bf16(a[m], b, acc[m][nf], 0, 0, 0);
    }
    __syncthreads();
  }
  int frow = lane & 15;
  int rbase = (lane >> 4) * 4;
  bool last = (t == kT - 1);
#pragma unroll
  for (int m = 0; m < 4; ++m) {
#pragma unroll
    for (int nf = 0; nf < 2; ++nf) {
      int gcol = bn0 + wv * 32 + nf * 16 + frow;
      float bh = b_h[l * kH + gcol];
#pragma unroll
      for (int q = 0; q < 4; ++q) {
        int grow = bm0 + m * 16 + rbase + q;
        size_t off = (size_t)grow * kH + gcol;
        float ht = tanhf(acc[m][nf][q] + C1c[off] + bh);
        float z = Zc[off];
        float hn = (1.0f - z) * hp[off] + z * ht;
        hout[off] = hn;
        if (last) hcur[(size_t)l * kB * kH + off] = hn;
      }
    }
  }
}

// outputs[b,t,:] = h_seq[7,t,b,:] @ Why + by ; A = h_seq[7] contiguous (4096 x 1024) f32
__global__ __launch_bounds__(256, 2) void out_gemm(
    const float* __restrict__ h7, const bf16* __restrict__ WhyT,
    const float* __restrict__ b_y, float* __restrict__ out) {
  __shared__ bf16 sA[BM * LDA];
  __shared__ bf16 sB[BN * LDB];
  int tid = threadIdx.x;
  int lane = tid & 63;
  int wv = tid >> 6;
  int bm0 = blockIdx.x * BM;
  int bn0 = blockIdx.y * BN;
  f32x4 acc[4][2] = {};
  int sr = tid >> 2;
  int sc = (tid & 3) * 8;
  for (int k0 = 0; k0 < kH; k0 += BK) {
    const float* pa = h7 + (size_t)(bm0 + sr) * kH + k0 + sc;
    float4 a0 = *(const float4*)pa;
    float4 a1 = *(const float4*)(pa + 4);
    *(bf16x8*)&sA[sr * LDA + sc] = cvt8(a0, a1);
#pragma unroll
    for (int p = 0; p < 2; ++p) {
      int idx = p * 256 + tid;
      int r = idx >> 2;
      int c = (idx & 3) * 8;
      *(bf16x8*)&sB[r * LDB + c] = *(const bf16x8*)(WhyT + (size_t)(bn0 + r) * kH + k0 + c);
    }
    __syncthreads();
    int frow = lane & 15;
    int fk = (lane >> 4) * 8;
    bf16x8 a[4];
#pragma unroll
    for (int m = 0; m < 4; ++m) a[m] = *(const bf16x8*)&sA[(m * 16 + frow) * LDA + fk];
#pragma unroll
    for (int nf = 0; nf < 2; ++nf) {
      int nr = wv * 32 + nf * 16 + frow;
      bf16x8 b = *(const bf16x8*)&sB[nr * LDB + fk];
#pragma unroll
      for (int m = 0; m < 4; ++m)
        acc[m][nf] = __builtin_amdgcn_mfma_f32_16x16x32_bf16(a[m], b, acc[m][nf], 0, 0, 0);
    }
    __syncthreads();
  }
  int frow = lane & 15;
  int rbase = (lane >> 4) * 4;
#pragma unroll
  for (int m = 0; m < 4; ++m) {
#pragma unroll
    for (int nf = 0; nf < 2; ++nf) {
      int gcol = bn0 + wv * 32 + nf * 16 + frow;
      float by = b_y[gcol];
#pragma unroll
      for (int q = 0; q < 4; ++q) {
        int grow = bm0 + m * 16 + rbase + q;  // = t*512 + b
        int tt = grow >> 9;
        int bb = grow & 511;
        out[((size_t)bb * kT + tt) * kH + gcol] = acc[m][nf][q] + by;
      }
    }
  }
}

extern "C" void kernel_launch(void* const* d_in, const int* in_sizes, int n_in,
                              void* d_out, int out_size, void* d_ws, size_t ws_size,
                              hipStream_t stream) {
  const float* x     = (const float*)d_in[0];
  const float* hprev = (const float*)d_in[1];
  const float* Wxz   = (const float*)d_in[2];
  const float* Whz   = (const float*)d_in[3];
  const float* bz    = (const float*)d_in[4];
  const float* Wxr   = (const float*)d_in[5];
  const float* Whr   = (const float*)d_in[6];
  const float* br    = (const float*)d_in[7];
  const float* Wxh   = (const float*)d_in[8];
  const float* Whh   = (const float*)d_in[9];
  const float* bh    = (const float*)d_in[10];
  const float* Why   = (const float*)d_in[11];
  const float* by    = (const float*)d_in[12];

  float* out  = (float*)d_out;                         // (B, T, O)
  float* hseq = out + (size_t)kB * kT * kH;            // (L, T, B, H)
  float* hcur = hseq + (size_t)kL * kT * kB * kH;      // (L, B, H)

  // ws layout: 49 transposed bf16 1024x1024 weights, then Z/C1 f32 and RH bf16 per-cell slots
  bf16* wt = (bf16*)d_ws;
  char* p = (char*)d_ws + (size_t)49 * kH * kH * 2;
  float* Zs  = (float*)p; p += (size_t)8 * kB * kH * 4;
  float* C1s = (float*)p; p += (size_t)8 * kB * kH * 4;
  bf16*  RHs = (bf16*)p;

  wconv_kernel<<<dim3(16, 16, 49), 256, 0, stream>>>(Wxz, Whz, Wxr, Whr, Wxh, Whh, Why, wt);

  for (int dg = 0; dg <= 14; ++dg) {
    int t_lo = dg > 7 ? dg - 7 : 0;
    int t_hi = dg < 7 ? dg : 7;
    int nc = t_hi - t_lo + 1;
    gru_phase1<<<dim3(8, 8, nc), 256, 0, stream>>>(x, hprev, hseq, wt, bz, br, Zs, C1s, RHs, dg, t_lo);
    gru_phase2<<<dim3(8, 8, nc), 256, 0, stream>>>(hprev, hseq, hcur, wt, bh, Zs, C1s, RHs, dg, t_lo);
  }

  out_gemm<<<dim3(64, 8), 256, 0, stream>>>(hseq + (size_t)7 * kT * kB * kH,
                                            wt + (size_t)48 * kH * kH, by, out);
}

// Round 2
// 1649.153 us; speedup vs baseline: 1.2620x; 1.2620x over previous
//
#include <hip/hip_runtime.h>
#include <hip/hip_bf16.h>

typedef __bf16 bf16;
typedef __attribute__((ext_vector_type(8))) __bf16 bf16x8;
typedef __attribute__((ext_vector_type(4))) float f32x4;

constexpr int kH = 1024;   // hidden = input = output dim
constexpr int kB = 512;    // batch
constexpr int kT = 8;      // timesteps actually used (= nlayers in reference loop)
constexpr int kL = 8;      // layers
constexpr int kS = 128;    // seq len of x

constexpr int BM = 64, BN = 128, BK = 32;
constexpr int LDA = BK + 8;   // padded LDS k-stride (bf16 elems) -> 2-way-max bank aliasing
constexpr int LDB = BK + 8;

__device__ __forceinline__ float sigmoidf_(float v) { return 1.0f / (1.0f + __expf(-v)); }

// Bijective XCD-chunk swizzle (m204): consecutive work-ids land on the SAME XCD
// so M-tiles sharing a B panel hit that XCD's private L2 instead of re-fetching.
__device__ __forceinline__ int xcd_swizzle(int g, int nwg) {
  int q = nwg >> 3, r = nwg & 7;
  int xcd = g & 7, idx = g >> 3;
  return (xcd < r ? xcd * (q + 1) : r * (q + 1) + (xcd - r) * q) + idx;
}

__device__ __forceinline__ bf16x8 cvt8(float4 a, float4 b) {
  bf16x8 o;
  o[0] = (bf16)a.x; o[1] = (bf16)a.y; o[2] = (bf16)a.z; o[3] = (bf16)a.w;
  o[4] = (bf16)b.x; o[5] = (bf16)b.y; o[6] = (bf16)b.z; o[7] = (bf16)b.w;
  return o;
}

// Transpose+convert each 1024x1024 f32 W (row-major KxN) -> bf16 W^T (NxK).
// mats 0..47 = {Wxz,Whz,Wxr,Whr,Wxh,Whh}[mat/8] layer (mat%8); mat 48 = Why.
__global__ __launch_bounds__(256) void wconv_kernel(
    const float* __restrict__ Wxz, const float* __restrict__ Whz,
    const float* __restrict__ Wxr, const float* __restrict__ Whr,
    const float* __restrict__ Wxh, const float* __restrict__ Whh,
    const float* __restrict__ Why, bf16* __restrict__ wt) {
  __shared__ float tile[64][65];
  int mat = blockIdx.z;
  const float* src;
  if (mat < 48) {
    int g = mat >> 3;
    const float* bases[6] = {Wxz, Whz, Wxr, Whr, Wxh, Whh};
    src = bases[g] + (size_t)(mat & 7) * kH * kH;
  } else {
    src = Why;
  }
  bf16* dst = wt + (size_t)mat * kH * kH;
  int k0 = blockIdx.x * 64;   // source row (K) range
  int n0 = blockIdx.y * 64;   // source col (N) range
  int tid = threadIdx.x;
  int cl = (tid & 15) * 4;
  int rw = tid >> 4;
#pragma unroll
  for (int i = 0; i < 4; ++i) {
    int r = rw + i * 16;
    float4 v = *(const float4*)(src + (size_t)(k0 + r) * kH + n0 + cl);
    tile[r][cl] = v.x; tile[r][cl + 1] = v.y; tile[r][cl + 2] = v.z; tile[r][cl + 3] = v.w;
  }
  __syncthreads();
#pragma unroll
  for (int p = 0; p < 2; ++p) {
    int idx = p * 256 + tid;
    int n = idx >> 3;
    int koff = (idx & 7) * 8;
    bf16x8 o;
#pragma unroll
    for (int i = 0; i < 8; ++i) o[i] = (bf16)tile[koff + i][n];
    *(bf16x8*)(dst + (size_t)(n0 + n) * kH + k0 + koff) = o;
  }
}

// Phase 1 of GRU cell (t,l): z = sigmoid(inp@Wxz + hp@Whz + bz),
// r = sigmoid(inp@Wxr + hp@Whr + br), c1 = inp@Wxh.
// Stores Z (f32), C1 (f32), RH = r*hp (bf16) into per-cell ws slots.
__global__ __launch_bounds__(256, 2) void gru_phase1(
    const float* __restrict__ x, const float* __restrict__ hprev,
    const float* __restrict__ hseq, const bf16* __restrict__ wt,
    const float* __restrict__ b_z, const float* __restrict__ b_r,
    float* __restrict__ Zs, float* __restrict__ C1s, bf16* __restrict__ RHs,
    int diag, int t_lo) {
  int w = xcd_swizzle(blockIdx.x, gridDim.x);
  int bm0 = (w & 7) * BM;
  int bn0 = ((w >> 3) & 7) * BN;
  int cell = w >> 6;
  int t = t_lo + cell;
  int l = diag - t;
  const float* inp; int inp_stride;
  if (l == 0) { inp = x + (size_t)t * kH; inp_stride = kS * kH; }
  else        { inp = hseq + ((size_t)((l - 1) * kT + t)) * kB * kH; inp_stride = kH; }
  const float* hp = (t == 0) ? hprev + (size_t)l * kB * kH
                             : hseq + ((size_t)(l * kT + (t - 1))) * kB * kH;
  const bf16* Wp[5];
#pragma unroll
  for (int g = 0; g < 5; ++g) Wp[g] = wt + ((size_t)g * 8 + l) * kH * kH;
  float* Zc  = Zs  + (size_t)cell * kB * kH;
  float* C1c = C1s + (size_t)cell * kB * kH;
  bf16*  RHc = RHs + (size_t)cell * kB * kH;

  __shared__ bf16 sInp[BM * LDA];
  __shared__ bf16 sHp[BM * LDA];
  __shared__ bf16 sB[5][BN * LDB];

  int tid = threadIdx.x;
  int lane = tid & 63;
  int wv = tid >> 6;

  f32x4 zacc[4][2] = {};
  f32x4 racc[4][2] = {};
  f32x4 cacc[4][2] = {};

  int sr = tid >> 2;        // 0..63
  int sc = (tid & 3) * 8;   // 0,8,16,24

  for (int k0 = 0; k0 < kH; k0 += BK) {
    {
      const float* pi = inp + (size_t)(bm0 + sr) * inp_stride + k0 + sc;
      float4 a0 = *(const float4*)pi;
      float4 a1 = *(const float4*)(pi + 4);
      *(bf16x8*)&sInp[sr * LDA + sc] = cvt8(a0, a1);
      const float* ph = hp + (size_t)(bm0 + sr) * kH + k0 + sc;
      float4 h0 = *(const float4*)ph;
      float4 h1 = *(const float4*)(ph + 4);
      *(bf16x8*)&sHp[sr * LDA + sc] = cvt8(h0, h1);
    }
#pragma unroll
    for (int g = 0; g < 5; ++g) {
#pragma unroll
      for (int p = 0; p < 2; ++p) {
        int idx = p * 256 + tid;
        int r = idx >> 2;
        int c = (idx & 3) * 8;
        *(bf16x8*)&sB[g][r * LDB + c] =
            *(const bf16x8*)(Wp[g] + (size_t)(bn0 + r) * kH + k0 + c);
      }
    }
    __syncthreads();
    int frow = lane & 15;
    int fk = (lane >> 4) * 8;
    bf16x8 ai[4], ah[4];
#pragma unroll
    for (int m = 0; m < 4; ++m) {
      ai[m] = *(const bf16x8*)&sInp[(m * 16 + frow) * LDA + fk];
      ah[m] = *(const bf16x8*)&sHp[(m * 16 + frow) * LDA + fk];
    }
#pragma unroll
    for (int nf = 0; nf < 2; ++nf) {
      int nr = wv * 32 + nf * 16 + frow;
      bf16x8 bxz = *(const bf16x8*)&sB[0][nr * LDB + fk];
      bf16x8 bhz = *(const bf16x8*)&sB[1][nr * LDB + fk];
      bf16x8 bxr = *(const bf16x8*)&sB[2][nr * LDB + fk];
      bf16x8 bhr = *(const bf16x8*)&sB[3][nr * LDB + fk];
      bf16x8 bxh = *(const bf16x8*)&sB[4][nr * LDB + fk];
#pragma unroll
      for (int m = 0; m < 4; ++m) {
        zacc[m][nf] = __builtin_amdgcn_mfma_f32_16x16x32_bf16(ai[m], bxz, zacc[m][nf], 0, 0, 0);
        zacc[m][nf] = __builtin_amdgcn_mfma_f32_16x16x32_bf16(ah[m], bhz, zacc[m][nf], 0, 0, 0);
        racc[m][nf] = __builtin_amdgcn_mfma_f32_16x16x32_bf16(ai[m], bxr, racc[m][nf], 0, 0, 0);
        racc[m][nf] = __builtin_amdgcn_mfma_f32_16x16x32_bf16(ah[m], bhr, racc[m][nf], 0, 0, 0);
        cacc[m][nf] = __builtin_amdgcn_mfma_f32_16x16x32_bf16(ai[m], bxh, cacc[m][nf], 0, 0, 0);
      }
    }
    __syncthreads();
  }
  // epilogue: C/D layout col=lane&15, row=(lane>>4)*4+q (m89-verified)
  int frow = lane & 15;
  int rbase = (lane >> 4) * 4;
#pragma unroll
  for (int m = 0; m < 4; ++m) {
#pragma unroll
    for (int nf = 0; nf < 2; ++nf) {
      int gcol = bn0 + wv * 32 + nf * 16 + frow;
      float bz = b_z[l * kH + gcol];
      float br = b_r[l * kH + gcol];
#pragma unroll
      for (int q = 0; q < 4; ++q) {
        int grow = bm0 + m * 16 + rbase + q;
        size_t off = (size_t)grow * kH + gcol;
        float z = sigmoidf_(zacc[m][nf][q] + bz);
        float r = sigmoidf_(racc[m][nf][q] + br);
        float hpv = hp[off];
        Zc[off] = z;
        C1c[off] = cacc[m][nf][q];
        RHc[off] = (bf16)(r * hpv);
      }
    }
  }
}

// Phase 2: h = (1-z)*hp + z*tanh(C1 + RH@Whh + bh); writes h_seq[l][t] (+ h_current at t==7)
__global__ __launch_bounds__(256, 2) void gru_phase2(
    const float* __restrict__ hprev, float* __restrict__ hseq,
    float* __restrict__ hcur, const bf16* __restrict__ wt,
    const float* __restrict__ b_h, const float* __restrict__ Zs,
    const float* __restrict__ C1s, const bf16* __restrict__ RHs,
    int diag, int t_lo) {
  int w = xcd_swizzle(blockIdx.x, gridDim.x);
  int bm0 = (w & 7) * BM;
  int bn0 = ((w >> 3) & 7) * BN;
  int cell = w >> 6;
  int t = t_lo + cell;
  int l = diag - t;
  const bf16* Whh = wt + ((size_t)5 * 8 + l) * kH * kH;
  const float* hp = (t == 0) ? hprev + (size_t)l * kB * kH
                             : hseq + ((size_t)(l * kT + (t - 1))) * kB * kH;
  float* hout = hseq + ((size_t)(l * kT + t)) * kB * kH;
  const float* Zc  = Zs  + (size_t)cell * kB * kH;
  const float* C1c = C1s + (size_t)cell * kB * kH;
  const bf16*  RHc = RHs + (size_t)cell * kB * kH;

  __shared__ bf16 sA[BM * LDA];
  __shared__ bf16 sB[BN * LDB];

  int tid = threadIdx.x;
  int lane = tid & 63;
  int wv = tid >> 6;

  f32x4 acc[4][2] = {};
  int sr = tid >> 2;
  int sc = (tid & 3) * 8;

  for (int k0 = 0; k0 < kH; k0 += BK) {
    *(bf16x8*)&sA[sr * LDA + sc] = *(const bf16x8*)(RHc + (size_t)(bm0 + sr) * kH + k0 + sc);
#pragma unroll
    for (int p = 0; p < 2; ++p) {
      int idx = p * 256 + tid;
      int r = idx >> 2;
      int c = (idx & 3) * 8;
      *(bf16x8*)&sB[r * LDB + c] = *(const bf16x8*)(Whh + (size_t)(bn0 + r) * kH + k0 + c);
    }
    __syncthreads();
    int frow = lane & 15;
    int fk = (lane >> 4) * 8;
    bf16x8 a[4];
#pragma unroll
    for (int m = 0; m < 4; ++m) a[m] = *(const bf16x8*)&sA[(m * 16 + frow) * LDA + fk];
#pragma unroll
    for (int nf = 0; nf < 2; ++nf) {
      int nr = wv * 32 + nf * 16 + frow;
      bf16x8 b = *(const bf16x8*)&sB[nr * LDB + fk];
#pragma unroll
      for (int m = 0; m < 4; ++m)
        acc[m][nf] = __builtin_amdgcn_mfma_f32_16x16x32_bf16(a[m], b, acc[m][nf], 0, 0, 0);
    }
    __syncthreads();
  }
  int frow = lane & 15;
  int rbase = (lane >> 4) * 4;
  bool last = (t == kT - 1);
#pragma unroll
  for (int m = 0; m < 4; ++m) {
#pragma unroll
    for (int nf = 0; nf < 2; ++nf) {
      int gcol = bn0 + wv * 32 + nf * 16 + frow;
      float bh = b_h[l * kH + gcol];
#pragma unroll
      for (int q = 0; q < 4; ++q) {
        int grow = bm0 + m * 16 + rbase + q;
        size_t off = (size_t)grow * kH + gcol;
        float ht = tanhf(acc[m][nf][q] + C1c[off] + bh);
        float z = Zc[off];
        float hn = (1.0f - z) * hp[off] + z * ht;
        hout[off] = hn;
        if (last) hcur[(size_t)l * kB * kH + off] = hn;
      }
    }
  }
}

// outputs[b,t,:] = h_seq[7,t,b,:] @ Why + by ; A = h_seq[7] contiguous (4096 x 1024) f32
__global__ __launch_bounds__(256, 2) void out_gemm(
    const float* __restrict__ h7, const bf16* __restrict__ WhyT,
    const float* __restrict__ b_y, float* __restrict__ out) {
  __shared__ bf16 sA[BM * LDA];
  __shared__ bf16 sB[BN * LDB];
  int w = xcd_swizzle(blockIdx.x, gridDim.x);
  int bm0 = (w & 63) * BM;   // 64 M-tiles of 64 rows (4096 total)
  int bn0 = (w >> 6) * BN;   // 8 N-tiles of 128
  int tid = threadIdx.x;
  int lane = tid & 63;
  int wv = tid >> 6;
  f32x4 acc[4][2] = {};
  int sr = tid >> 2;
  int sc = (tid & 3) * 8;
  for (int k0 = 0; k0 < kH; k0 += BK) {
    const float* pa = h7 + (size_t)(bm0 + sr) * kH + k0 + sc;
    float4 a0 = *(const float4*)pa;
    float4 a1 = *(const float4*)(pa + 4);
    *(bf16x8*)&sA[sr * LDA + sc] = cvt8(a0, a1);
#pragma unroll
    for (int p = 0; p < 2; ++p) {
      int idx = p * 256 + tid;
      int r = idx >> 2;
      int c = (idx & 3) * 8;
      *(bf16x8*)&sB[r * LDB + c] = *(const bf16x8*)(WhyT + (size_t)(bn0 + r) * kH + k0 + c);
    }
    __syncthreads();
    int frow = lane & 15;
    int fk = (lane >> 4) * 8;
    bf16x8 a[4];
#pragma unroll
    for (int m = 0; m < 4; ++m) a[m] = *(const bf16x8*)&sA[(m * 16 + frow) * LDA + fk];
#pragma unroll
    for (int nf = 0; nf < 2; ++nf) {
      int nr = wv * 32 + nf * 16 + frow;
      bf16x8 b = *(const bf16x8*)&sB[nr * LDB + fk];
#pragma unroll
      for (int m = 0; m < 4; ++m)
        acc[m][nf] = __builtin_amdgcn_mfma_f32_16x16x32_bf16(a[m], b, acc[m][nf], 0, 0, 0);
    }
    __syncthreads();
  }
  int frow = lane & 15;
  int rbase = (lane >> 4) * 4;
#pragma unroll
  for (int m = 0; m < 4; ++m) {
#pragma unroll
    for (int nf = 0; nf < 2; ++nf) {
      int gcol = bn0 + wv * 32 + nf * 16 + frow;
      float by = b_y[gcol];
#pragma unroll
      for (int q = 0; q < 4; ++q) {
        int grow = bm0 + m * 16 + rbase + q;  // = t*512 + b
        int tt = grow >> 9;
        int bb = grow & 511;
        out[((size_t)bb * kT + tt) * kH + gcol] = acc[m][nf][q] + by;
      }
    }
  }
}

extern "C" void kernel_launch(void* const* d_in, const int* in_sizes, int n_in,
                              void* d_out, int out_size, void* d_ws, size_t ws_size,
                              hipStream_t stream) {
  const float* x     = (const float*)d_in[0];
  const float* hprev = (const float*)d_in[1];
  const float* Wxz   = (const float*)d_in[2];
  const float* Whz   = (const float*)d_in[3];
  const float* bz    = (const float*)d_in[4];
  const float* Wxr   = (const float*)d_in[5];
  const float* Whr   = (const float*)d_in[6];
  const float* br    = (const float*)d_in[7];
  const float* Wxh   = (const float*)d_in[8];
  const float* Whh   = (const float*)d_in[9];
  const float* bh    = (const float*)d_in[10];
  const float* Why   = (const float*)d_in[11];
  const float* by    = (const float*)d_in[12];

  float* out  = (float*)d_out;                         // (B, T, O)
  float* hseq = out + (size_t)kB * kT * kH;            // (L, T, B, H)
  float* hcur = hseq + (size_t)kL * kT * kB * kH;      // (L, B, H)

  // ws layout: 49 transposed bf16 1024x1024 weights, then Z/C1 f32 and RH bf16 per-cell slots
  bf16* wt = (bf16*)d_ws;
  char* p = (char*)d_ws + (size_t)49 * kH * kH * 2;
  float* Zs  = (float*)p; p += (size_t)8 * kB * kH * 4;
  float* C1s = (float*)p; p += (size_t)8 * kB * kH * 4;
  bf16*  RHs = (bf16*)p;

  wconv_kernel<<<dim3(16, 16, 49), 256, 0, stream>>>(Wxz, Whz, Wxr, Whr, Wxh, Whh, Why, wt);

  for (int dg = 0; dg <= 14; ++dg) {
    int t_lo = dg > 7 ? dg - 7 : 0;
    int t_hi = dg < 7 ? dg : 7;
    int nc = t_hi - t_lo + 1;
    gru_phase1<<<dim3(64 * nc), 256, 0, stream>>>(x, hprev, hseq, wt, bz, br, Zs, C1s, RHs, dg, t_lo);
    gru_phase2<<<dim3(64 * nc), 256, 0, stream>>>(hprev, hseq, hcur, wt, bh, Zs, C1s, RHs, dg, t_lo);
  }

  out_gemm<<<dim3(512), 256, 0, stream>>>(hseq + (size_t)7 * kT * kB * kH,
                                          wt + (size_t)48 * kH * kH, by, out);
}